// Round 7
// baseline (772.963 us; speedup 1.0000x reference)
//
#include <hip/hip_runtime.h>
#include <math.h>

// GCN 3-layer forward, N=100000, E=3200000, F=256 -> 8 -> 4 -> 16.
// Round 7: round-5's replay-proven preprocessing (count/scan/place/deg,
// bucket-grouped records) + NEW broadcast-scan layer kernels: per bucket,
// records staged to LDS in tiles; each thread owns (node, feature-slice) and
// scans every record with predicated FMAs. Zero atomics / shuffles / CSR /
// in-place rewrites in the aggregation path (round-6's replay race removed).

#define N_NODES 100000
#define N_EDGES 3200000
#define BN 64                        // nodes per bucket
#define NBUK 1563                    // ceil(N/BN)
#define NCHUNK 256
#define CHUNK_E (N_EDGES / NCHUNK)   // 12500
#define RT 1024                      // records per LDS tile in layer kernels

__device__ __forceinline__ float eluf(float v) { return v > 0.0f ? v : expm1f(v); }

__device__ __forceinline__ void lds_add(float* p, float v) { unsafeAtomicAdd(p, v); }

__device__ __forceinline__ int ld_edge(const void* __restrict__ raw, int is64, long long idx) {
  return is64 ? (int)((const long long*)raw)[idx] : ((const int*)raw)[idx];
}

// Detect whether edge_index arrived as int64 (odd u32 words of first 64 all 0)
__global__ void detect_kernel(const unsigned int* __restrict__ ei, int* __restrict__ flag) {
  if (blockIdx.x == 0 && threadIdx.x == 0) {
    int is64 = 1;
    for (int i = 0; i < 32; ++i)
      if (ei[2 * i + 1] != 0u) { is64 = 0; break; }
    *flag = is64;
  }
}

// Phase A: per-(chunk,bucket) edge counts via LDS histogram (int atomics).
__global__ __launch_bounds__(512) void count_kernel(const void* __restrict__ raw,
                                                    const int* __restrict__ flag,
                                                    int* __restrict__ cnt) {
  __shared__ int c[NBUK];
  const int tid = threadIdx.x;
  for (int i = tid; i < NBUK; i += 512) c[i] = 0;
  __syncthreads();
  const int is64 = *flag;
  const int c0 = blockIdx.x * CHUNK_E;
  for (int e = c0 + tid; e < c0 + CHUNK_E; e += 512) {
    int d = ld_edge(raw, is64, (long long)N_EDGES + e);
    if ((unsigned)d < (unsigned)N_NODES) atomicAdd(&c[d >> 6], 1);
  }
  __syncthreads();
  for (int i = tid; i < NBUK; i += 512) cnt[blockIdx.x * NBUK + i] = c[i];
}

// Column-scan cnt (exclusive per bucket over chunks) + exclusive scan of
// bucket totals -> bucketBase[NBUK+1]. One block, 1024 threads, 2 buckets/thread.
__global__ __launch_bounds__(1024) void scan_kernel(int* __restrict__ cnt,
                                                    int* __restrict__ bucketBase) {
  __shared__ int sdata[1024];
  __shared__ int sTA;
  const int t = threadIdx.x;
  int T0 = 0;
  {
    int run = 0;
    for (int c = 0; c < NCHUNK; ++c) {
      int idx = c * NBUK + t;
      int v = cnt[idx];
      cnt[idx] = run;
      run += v;
    }
    T0 = run;
  }
  const int b1 = 1024 + t;
  int T1 = 0;
  if (b1 < NBUK) {
    int run = 0;
    for (int c = 0; c < NCHUNK; ++c) {
      int idx = c * NBUK + b1;
      int v = cnt[idx];
      cnt[idx] = run;
      run += v;
    }
    T1 = run;
  }
  sdata[t] = T0;
  __syncthreads();
  for (int off = 1; off < 1024; off <<= 1) {
    int v = (t >= off) ? sdata[t - off] : 0;
    __syncthreads();
    sdata[t] += v;
    __syncthreads();
  }
  int incl0 = sdata[t];
  if (t == 1023) sTA = sdata[1023];
  __syncthreads();
  const int TA = sTA;
  sdata[t] = T1;
  __syncthreads();
  for (int off = 1; off < 1024; off <<= 1) {
    int v = (t >= off) ? sdata[t - off] : 0;
    __syncthreads();
    sdata[t] += v;
    __syncthreads();
  }
  int incl1 = sdata[t];
  bucketBase[t] = incl0 - T0;
  if (b1 < NBUK) bucketBase[b1] = TA + incl1 - T1;
  if (b1 == NBUK - 1) bucketBase[NBUK] = TA + incl1;
}

// Phase C: place records {src:17b | local:6b<<17, w} into bucket-grouped order.
// Every counted position gets written (invalid src -> zero-weight record).
__global__ __launch_bounds__(512) void place_kernel(const void* __restrict__ raw,
                                                    const int* __restrict__ flag,
                                                    const float* __restrict__ w,
                                                    const int* __restrict__ cnt,
                                                    const int* __restrict__ bucketBase,
                                                    int2* __restrict__ recs) {
  __shared__ int cur[NBUK];
  const int tid = threadIdx.x;
  for (int i = tid; i < NBUK; i += 512)
    cur[i] = cnt[blockIdx.x * NBUK + i] + bucketBase[i];
  __syncthreads();
  const int is64 = *flag;
  const int c0 = blockIdx.x * CHUNK_E;
  for (int e = c0 + tid; e < c0 + CHUNK_E; e += 512) {
    int s = ld_edge(raw, is64, e);
    int d = ld_edge(raw, is64, (long long)N_EDGES + e);
    if ((unsigned)d >= (unsigned)N_NODES) continue;
    float wv = w[e];
    if ((unsigned)s >= (unsigned)N_NODES) { s = 0; wv = 0.0f; }
    int bkt = d >> 6, loc = d & 63;
    int pos = atomicAdd(&cur[bkt], 1);
    recs[pos] = make_int2(s | (loc << 17), __float_as_int(wv));
  }
}

// Weighted degree per bucket via native LDS float adds -> dis = rsqrt(deg + 1).
__global__ __launch_bounds__(256) void deg_kernel(const int2* __restrict__ recs,
                                                  const int* __restrict__ bucketBase,
                                                  float* __restrict__ dis) {
  __shared__ float acc[BN];
  const int b = blockIdx.x, tid = threadIdx.x;
  if (tid < BN) acc[tid] = 0.0f;
  __syncthreads();
  const int beg = bucketBase[b], end = bucketBase[b + 1];
  for (int i = beg + tid; i < end; i += 256) {
    int2 r = recs[i];
    lds_add(&acc[(r.x >> 17) & 63], __int_as_float(r.y));
  }
  __syncthreads();
  int n = b * BN + tid;
  if (tid < BN && n < N_NODES) dis[n] = rsqrtf(acc[tid] + 1.0f);
}

// m1s[n] = dis[n] * (x[n] @ W1); one wave per node row (64 lanes x float4).
__global__ __launch_bounds__(256) void transform1_kernel(const float* __restrict__ x,
                                                         const float* __restrict__ W1,
                                                         const float* __restrict__ dis,
                                                         float* __restrict__ m1s) {
  const int lane = threadIdx.x & 63;
  const int gwave = blockIdx.x * 4 + (threadIdx.x >> 6);
  const int nwaves = gridDim.x * 4;
  float wreg[4][8];
#pragma unroll
  for (int i = 0; i < 4; ++i)
#pragma unroll
    for (int j = 0; j < 8; ++j)
      wreg[i][j] = W1[(lane * 4 + i) * 8 + j];
  for (int n = gwave; n < N_NODES; n += nwaves) {
    float4 xv = *(const float4*)(x + (size_t)n * 256 + lane * 4);
    float acc[8];
#pragma unroll
    for (int j = 0; j < 8; ++j)
      acc[j] = xv.x * wreg[0][j] + xv.y * wreg[1][j] + xv.z * wreg[2][j] + xv.w * wreg[3][j];
#pragma unroll
    for (int off = 32; off > 0; off >>= 1)
#pragma unroll
      for (int j = 0; j < 8; ++j)
        acc[j] += __shfl_down(acc[j], off);
    if (lane == 0) {
      float di = dis[n];
      float4* o = (float4*)(m1s + (size_t)n * 8);
      o[0] = make_float4(di * acc[0], di * acc[1], di * acc[2], di * acc[3]);
      o[1] = make_float4(di * acc[4], di * acc[5], di * acc[6], di * acc[7]);
    }
  }
}

// Layer 1 (broadcast-scan): thread (loc = tid>>2, p = tid&3) owns node loc,
// floats {2p,2p+1} of 8. acc = sum over bucket records hitting loc of
// w * m1s[s]; epilogue: h = elu(dis*(acc + m1s[n]) + b1); m2s = dis*(h@W2).
__global__ __launch_bounds__(256) void layer1_kernel(const int2* __restrict__ recs,
                                                     const int* __restrict__ bucketBase,
                                                     const float* __restrict__ m1s,
                                                     const float* __restrict__ dis,
                                                     const float* __restrict__ b1,
                                                     const float* __restrict__ W2,
                                                     float* __restrict__ m2s) {
  __shared__ int2 rbuf[RT];
  __shared__ float hacc[BN][8];
  const int b = blockIdx.x, tid = threadIdx.x;
  const int beg = bucketBase[b], end = bucketBase[b + 1];
  const int loc = tid >> 2, p = tid & 3;
  float a0 = 0.f, a1 = 0.f;
  for (int t0 = beg; t0 < end; t0 += RT) {
    const int nrec = min(RT, end - t0);
    __syncthreads();
    for (int i = tid; i < nrec; i += 256) rbuf[i] = recs[t0 + i];
    __syncthreads();
#pragma unroll 4
    for (int i = 0; i < nrec; ++i) {
      int2 r = rbuf[i];
      if (((r.x >> 17) & 63) == loc) {
        int s = r.x & 0x1FFFF;
        float wv = __int_as_float(r.y);
        float2 v = *(const float2*)(m1s + (size_t)s * 8 + 2 * p);
        a0 += wv * v.x;
        a1 += wv * v.y;
      }
    }
  }
  hacc[loc][2 * p] = a0;
  hacc[loc][2 * p + 1] = a1;
  __syncthreads();
  if (tid < BN) {
    int n = b * BN + tid;
    if (n < N_NODES) {
      float di = dis[n];
      const float4* mm = (const float4*)(m1s + (size_t)n * 8);
      float4 s0 = mm[0], s1 = mm[1];
      float h[8];
      h[0] = eluf(di * (hacc[tid][0] + s0.x) + b1[0]);
      h[1] = eluf(di * (hacc[tid][1] + s0.y) + b1[1]);
      h[2] = eluf(di * (hacc[tid][2] + s0.z) + b1[2]);
      h[3] = eluf(di * (hacc[tid][3] + s0.w) + b1[3]);
      h[4] = eluf(di * (hacc[tid][4] + s1.x) + b1[4]);
      h[5] = eluf(di * (hacc[tid][5] + s1.y) + b1[5]);
      h[6] = eluf(di * (hacc[tid][6] + s1.z) + b1[6]);
      h[7] = eluf(di * (hacc[tid][7] + s1.w) + b1[7]);
      float o0 = 0.f, o1 = 0.f, o2 = 0.f, o3 = 0.f;
#pragma unroll
      for (int i = 0; i < 8; ++i) {
        float hi = h[i];
        o0 += hi * W2[i * 4 + 0];
        o1 += hi * W2[i * 4 + 1];
        o2 += hi * W2[i * 4 + 2];
        o3 += hi * W2[i * 4 + 3];
      }
      *(float4*)(m2s + (size_t)n * 4) = make_float4(di * o0, di * o1, di * o2, di * o3);
    }
  }
}

// Layer 2 (broadcast-scan): thread (loc, p) owns node loc, float p of 4.
// h2s = dis * elu(dis*(acc + m2s[n]) + b2).
__global__ __launch_bounds__(256) void layer2_kernel(const int2* __restrict__ recs,
                                                     const int* __restrict__ bucketBase,
                                                     const float* __restrict__ m2s,
                                                     const float* __restrict__ dis,
                                                     const float* __restrict__ b2,
                                                     float* __restrict__ h2s) {
  __shared__ int2 rbuf[RT];
  __shared__ float hacc[BN][4];
  const int b = blockIdx.x, tid = threadIdx.x;
  const int beg = bucketBase[b], end = bucketBase[b + 1];
  const int loc = tid >> 2, p = tid & 3;
  float a = 0.f;
  for (int t0 = beg; t0 < end; t0 += RT) {
    const int nrec = min(RT, end - t0);
    __syncthreads();
    for (int i = tid; i < nrec; i += 256) rbuf[i] = recs[t0 + i];
    __syncthreads();
#pragma unroll 4
    for (int i = 0; i < nrec; ++i) {
      int2 r = rbuf[i];
      if (((r.x >> 17) & 63) == loc) {
        int s = r.x & 0x1FFFF;
        a += __int_as_float(r.y) * m2s[(size_t)s * 4 + p];
      }
    }
  }
  hacc[loc][p] = a;
  __syncthreads();
  if (tid < BN) {
    int n = b * BN + tid;
    if (n < N_NODES) {
      float di = dis[n];
      float4 s = *(const float4*)(m2s + (size_t)n * 4);
      float4 r;
      r.x = di * eluf(di * (hacc[tid][0] + s.x) + b2[0]);
      r.y = di * eluf(di * (hacc[tid][1] + s.y) + b2[1]);
      r.z = di * eluf(di * (hacc[tid][2] + s.z) + b2[2]);
      r.w = di * eluf(di * (hacc[tid][3] + s.w) + b2[3]);
      *(float4*)(h2s + (size_t)n * 4) = r;
    }
  }
}

// Layer 3 (broadcast-scan): g = dis*(acc + h2s[n]); out = g @ W3 + b3.
// Epilogue: g staged in LDS; thread (loc,p) writes columns 4p..4p+3.
__global__ __launch_bounds__(256) void layer3_kernel(const int2* __restrict__ recs,
                                                     const int* __restrict__ bucketBase,
                                                     const float* __restrict__ h2s,
                                                     const float* __restrict__ dis,
                                                     const float* __restrict__ b3,
                                                     const float* __restrict__ W3,
                                                     float* __restrict__ out) {
  __shared__ int2 rbuf[RT];
  __shared__ float hacc[BN][4];
  __shared__ float gbuf[BN][4];
  const int b = blockIdx.x, tid = threadIdx.x;
  const int beg = bucketBase[b], end = bucketBase[b + 1];
  const int loc = tid >> 2, p = tid & 3;
  float a = 0.f;
  for (int t0 = beg; t0 < end; t0 += RT) {
    const int nrec = min(RT, end - t0);
    __syncthreads();
    for (int i = tid; i < nrec; i += 256) rbuf[i] = recs[t0 + i];
    __syncthreads();
#pragma unroll 4
    for (int i = 0; i < nrec; ++i) {
      int2 r = rbuf[i];
      if (((r.x >> 17) & 63) == loc) {
        int s = r.x & 0x1FFFF;
        a += __int_as_float(r.y) * h2s[(size_t)s * 4 + p];
      }
    }
  }
  hacc[loc][p] = a;
  __syncthreads();
  if (tid < BN) {
    int n = b * BN + tid;
    if (n < N_NODES) {
      float di = dis[n];
      float4 s = *(const float4*)(h2s + (size_t)n * 4);
      gbuf[tid][0] = di * (hacc[tid][0] + s.x);
      gbuf[tid][1] = di * (hacc[tid][1] + s.y);
      gbuf[tid][2] = di * (hacc[tid][2] + s.z);
      gbuf[tid][3] = di * (hacc[tid][3] + s.w);
    }
  }
  __syncthreads();
  int n = b * BN + loc;
  if (n < N_NODES) {
    float g0 = gbuf[loc][0], g1 = gbuf[loc][1], g2 = gbuf[loc][2], g3 = gbuf[loc][3];
    float o[4];
#pragma unroll
    for (int k = 0; k < 4; ++k) {
      int c = p * 4 + k;
      o[k] = b3[c] + g0 * W3[c] + g1 * W3[16 + c] + g2 * W3[32 + c] + g3 * W3[48 + c];
    }
    *(float4*)(out + (size_t)n * 16 + p * 4) = make_float4(o[0], o[1], o[2], o[3]);
  }
}

extern "C" void kernel_launch(void* const* d_in, const int* in_sizes, int n_in,
                              void* d_out, int out_size, void* d_ws, size_t ws_size,
                              hipStream_t stream) {
  const float* x = (const float*)d_in[0];
  const void* ei = d_in[1];
  const float* w = (const float*)d_in[2];
  const float* W1 = (const float*)d_in[3];
  const float* b1 = (const float*)d_in[4];
  const float* W2 = (const float*)d_in[5];
  const float* b2 = (const float*)d_in[6];
  const float* W3 = (const float*)d_in[7];
  const float* b3 = (const float*)d_in[8];
  float* out = (float*)d_out;
  float* ws = (float*)d_ws;

  // ws layout (4-byte words); recs first (8B-aligned at 0).
  int2* recs = (int2*)ws;                         // [E] int2      (6,400,000 w)
  float* m1s = ws + 6400000;                      // [8N]          (800,000 w)
  float* m2s = ws + 7200000;                      // [4N]          (400,000 w)
  float* h2s = ws + 7600000;                      // [4N]          (400,000 w)
  int* cnt = (int*)(ws + 8000000);                // [NCHUNK*NBUK] (400,128 w)
  int* bucketBase = (int*)(ws + 8400128);         // [NBUK+1]      (1,564 w)
  float* dis = ws + 8401692;                      // [N]           (100,000 w)
  int* flag = (int*)(ws + 8501692);               // [1]
  // total ~= 8,501,693 words ~= 34 MB

  detect_kernel<<<1, 64, 0, stream>>>((const unsigned int*)ei, flag);
  count_kernel<<<NCHUNK, 512, 0, stream>>>(ei, flag, cnt);
  scan_kernel<<<1, 1024, 0, stream>>>(cnt, bucketBase);
  place_kernel<<<NCHUNK, 512, 0, stream>>>(ei, flag, w, cnt, bucketBase, recs);
  deg_kernel<<<NBUK, 256, 0, stream>>>(recs, bucketBase, dis);
  transform1_kernel<<<4096, 256, 0, stream>>>(x, W1, dis, m1s);
  layer1_kernel<<<NBUK, 256, 0, stream>>>(recs, bucketBase, m1s, dis, b1, W2, m2s);
  layer2_kernel<<<NBUK, 256, 0, stream>>>(recs, bucketBase, m2s, dis, b2, h2s);
  layer3_kernel<<<NBUK, 256, 0, stream>>>(recs, bucketBase, h2s, dis, b3, W3, out);
}

// Round 8
// 321.872 us; speedup vs baseline: 2.4015x; 2.4015x over previous
//
#include <hip/hip_runtime.h>
#include <math.h>

// GCN 3-layer forward, N=100000, E=3200000, F=256 -> 8 -> 4 -> 16.
// Round 8: replay-proven preprocessing (count/scan/place/deg) + OUT-OF-PLACE
// per-bucket node-sort into recs2 + nodeOff CSR, then round-6's quad-gather
// layer kernels (4 lanes/node, register accumulation, shfl_xor reduce, zero
// atomics). Round 7's broadcast-scan (every thread scans all 2048 bucket
// records, 63/64 wasted) is replaced by O(deg) gathers.

#define N_NODES 100000
#define N_EDGES 3200000
#define BN 64                        // nodes per bucket
#define NBUK 1563                    // ceil(N/BN)
#define NCHUNK 64
#define CHUNK_E (N_EDGES / NCHUNK)   // 50000

__device__ __forceinline__ float eluf(float v) { return v > 0.0f ? v : expm1f(v); }

__device__ __forceinline__ void lds_add(float* p, float v) { unsafeAtomicAdd(p, v); }

__device__ __forceinline__ int ld_edge(const void* __restrict__ raw, int is64, long long idx) {
  return is64 ? (int)((const long long*)raw)[idx] : ((const int*)raw)[idx];
}

// Detect whether edge_index arrived as int64 (odd u32 words of first 64 all 0)
__global__ void detect_kernel(const unsigned int* __restrict__ ei, int* __restrict__ flag) {
  if (blockIdx.x == 0 && threadIdx.x == 0) {
    int is64 = 1;
    for (int i = 0; i < 32; ++i)
      if (ei[2 * i + 1] != 0u) { is64 = 0; break; }
    *flag = is64;
  }
}

// Phase A: per-(chunk,bucket) edge counts via LDS histogram (int atomics).
__global__ __launch_bounds__(512) void count_kernel(const void* __restrict__ raw,
                                                    const int* __restrict__ flag,
                                                    int* __restrict__ cnt) {
  __shared__ int c[NBUK];
  const int tid = threadIdx.x;
  for (int i = tid; i < NBUK; i += 512) c[i] = 0;
  __syncthreads();
  const int is64 = *flag;
  const int c0 = blockIdx.x * CHUNK_E;
  for (int e = c0 + tid; e < c0 + CHUNK_E; e += 512) {
    int d = ld_edge(raw, is64, (long long)N_EDGES + e);
    if ((unsigned)d < (unsigned)N_NODES) atomicAdd(&c[d >> 6], 1);
  }
  __syncthreads();
  for (int i = tid; i < NBUK; i += 512) cnt[blockIdx.x * NBUK + i] = c[i];
}

// Column-scan cnt (exclusive per bucket over chunks) + exclusive scan of
// bucket totals -> bucketBase[NBUK+1]. One block, 1024 threads, 2 buckets/thread.
__global__ __launch_bounds__(1024) void scan_kernel(int* __restrict__ cnt,
                                                    int* __restrict__ bucketBase) {
  __shared__ int sdata[1024];
  __shared__ int sTA;
  const int t = threadIdx.x;
  int T0 = 0;
  {
    int run = 0;
    for (int c = 0; c < NCHUNK; ++c) {
      int idx = c * NBUK + t;
      int v = cnt[idx];
      cnt[idx] = run;
      run += v;
    }
    T0 = run;
  }
  const int b1 = 1024 + t;
  int T1 = 0;
  if (b1 < NBUK) {
    int run = 0;
    for (int c = 0; c < NCHUNK; ++c) {
      int idx = c * NBUK + b1;
      int v = cnt[idx];
      cnt[idx] = run;
      run += v;
    }
    T1 = run;
  }
  sdata[t] = T0;
  __syncthreads();
  for (int off = 1; off < 1024; off <<= 1) {
    int v = (t >= off) ? sdata[t - off] : 0;
    __syncthreads();
    sdata[t] += v;
    __syncthreads();
  }
  int incl0 = sdata[t];
  if (t == 1023) sTA = sdata[1023];
  __syncthreads();
  const int TA = sTA;
  sdata[t] = T1;
  __syncthreads();
  for (int off = 1; off < 1024; off <<= 1) {
    int v = (t >= off) ? sdata[t - off] : 0;
    __syncthreads();
    sdata[t] += v;
    __syncthreads();
  }
  int incl1 = sdata[t];
  bucketBase[t] = incl0 - T0;
  if (b1 < NBUK) bucketBase[b1] = TA + incl1 - T1;
  if (b1 == NBUK - 1) bucketBase[NBUK] = TA + incl1;
}

// Phase C: place records {src:17b | local:6b<<17, w} into bucket-grouped order.
// Every counted position gets written (invalid src -> zero-weight record).
__global__ __launch_bounds__(512) void place_kernel(const void* __restrict__ raw,
                                                    const int* __restrict__ flag,
                                                    const float* __restrict__ w,
                                                    const int* __restrict__ cnt,
                                                    const int* __restrict__ bucketBase,
                                                    int2* __restrict__ recs) {
  __shared__ int cur[NBUK];
  const int tid = threadIdx.x;
  for (int i = tid; i < NBUK; i += 512)
    cur[i] = cnt[blockIdx.x * NBUK + i] + bucketBase[i];
  __syncthreads();
  const int is64 = *flag;
  const int c0 = blockIdx.x * CHUNK_E;
  for (int e = c0 + tid; e < c0 + CHUNK_E; e += 512) {
    int s = ld_edge(raw, is64, e);
    int d = ld_edge(raw, is64, (long long)N_EDGES + e);
    if ((unsigned)d >= (unsigned)N_NODES) continue;
    float wv = w[e];
    if ((unsigned)s >= (unsigned)N_NODES) { s = 0; wv = 0.0f; }
    int bkt = d >> 6, loc = d & 63;
    int pos = atomicAdd(&cur[bkt], 1);
    recs[pos] = make_int2(s | (loc << 17), __float_as_int(wv));
  }
}

// Weighted degree per bucket via native LDS float adds -> dis = rsqrt(deg + 1).
__global__ __launch_bounds__(256) void deg_kernel(const int2* __restrict__ recs,
                                                  const int* __restrict__ bucketBase,
                                                  float* __restrict__ dis) {
  __shared__ float acc[BN];
  const int b = blockIdx.x, tid = threadIdx.x;
  if (tid < BN) acc[tid] = 0.0f;
  __syncthreads();
  const int beg = bucketBase[b], end = bucketBase[b + 1];
  for (int i = beg + tid; i < end; i += 256) {
    int2 r = recs[i];
    lds_add(&acc[(r.x >> 17) & 63], __int_as_float(r.y));
  }
  __syncthreads();
  int n = b * BN + tid;
  if (tid < BN && n < N_NODES) dis[n] = rsqrtf(acc[tid] + 1.0f);
}

// Out-of-place node sort: per bucket, histogram by local node, wave-0 scan ->
// nodeOff CSR + cursors, then place records into recs2 (node-grouped).
__global__ __launch_bounds__(256) void nodesort_kernel(const int2* __restrict__ recs,
                                                       const int* __restrict__ bucketBase,
                                                       int2* __restrict__ recs2,
                                                       int* __restrict__ nodeOff) {
  __shared__ int hist[BN];
  __shared__ int cur[BN];
  const int b = blockIdx.x, tid = threadIdx.x;
  const int beg = bucketBase[b], end = bucketBase[b + 1];
  const int cnt = end - beg;
  if (tid < BN) hist[tid] = 0;
  __syncthreads();
  for (int i = tid; i < cnt; i += 256)
    atomicAdd(&hist[(recs[beg + i].x >> 17) & 63], 1);
  __syncthreads();
  if (tid < BN) {
    int v = hist[tid];
    int sc = v;
#pragma unroll
    for (int off = 1; off < BN; off <<= 1) {
      int u = __shfl_up(sc, off);
      if (tid >= off) sc += u;
    }
    int start = beg + sc - v;  // exclusive prefix within bucket
    cur[tid] = start;
    int n = b * BN + tid;
    if (n < N_NODES) nodeOff[n] = start;
  }
  __syncthreads();
  for (int i = tid; i < cnt; i += 256) {
    int2 r = recs[beg + i];
    int pos = atomicAdd(&cur[(r.x >> 17) & 63], 1);
    recs2[pos] = r;
  }
  if (b == 0 && tid == 0) nodeOff[N_NODES] = bucketBase[NBUK];
}

// m1s[n] = dis[n] * (x[n] @ W1); one wave per node row (64 lanes x float4).
__global__ __launch_bounds__(256) void transform1_kernel(const float* __restrict__ x,
                                                         const float* __restrict__ W1,
                                                         const float* __restrict__ dis,
                                                         float* __restrict__ m1s) {
  const int lane = threadIdx.x & 63;
  const int gwave = blockIdx.x * 4 + (threadIdx.x >> 6);
  const int nwaves = gridDim.x * 4;
  float wreg[4][8];
#pragma unroll
  for (int i = 0; i < 4; ++i)
#pragma unroll
    for (int j = 0; j < 8; ++j)
      wreg[i][j] = W1[(lane * 4 + i) * 8 + j];
  for (int n = gwave; n < N_NODES; n += nwaves) {
    float4 xv = *(const float4*)(x + (size_t)n * 256 + lane * 4);
    float acc[8];
#pragma unroll
    for (int j = 0; j < 8; ++j)
      acc[j] = xv.x * wreg[0][j] + xv.y * wreg[1][j] + xv.z * wreg[2][j] + xv.w * wreg[3][j];
#pragma unroll
    for (int off = 32; off > 0; off >>= 1)
#pragma unroll
      for (int j = 0; j < 8; ++j)
        acc[j] += __shfl_down(acc[j], off);
    if (lane == 0) {
      float di = dis[n];
      float4* o = (float4*)(m1s + (size_t)n * 8);
      o[0] = make_float4(di * acc[0], di * acc[1], di * acc[2], di * acc[3]);
      o[1] = make_float4(di * acc[4], di * acc[5], di * acc[6], di * acc[7]);
    }
  }
}

// Layer 1: 4 lanes per node; acc[8] in registers; h = elu(dis*(sum w*m1s[s]
// + m1s[n]) + b1); m2s = dis*(h@W2). No atomics.
__global__ __launch_bounds__(256) void layer1_kernel(const int2* __restrict__ recs2,
                                                     const int* __restrict__ nodeOff,
                                                     const float* __restrict__ m1s,
                                                     const float* __restrict__ dis,
                                                     const float* __restrict__ b1,
                                                     const float* __restrict__ W2,
                                                     float* __restrict__ m2s) {
  const int tid = threadIdx.x;
  const int l = tid & 3;
  const int n = blockIdx.x * BN + (tid >> 2);
  if (n >= N_NODES) return;
  const int beg = nodeOff[n], end = nodeOff[n + 1];
  float a[8] = {0, 0, 0, 0, 0, 0, 0, 0};
  for (int i = beg + l; i < end; i += 4) {
    int2 r = recs2[i];
    int s = r.x & 0x1FFFF;
    float wv = __int_as_float(r.y);
    const float4* f = (const float4*)(m1s + (size_t)s * 8);
    float4 v0 = f[0], v1 = f[1];
    a[0] += wv * v0.x; a[1] += wv * v0.y; a[2] += wv * v0.z; a[3] += wv * v0.w;
    a[4] += wv * v1.x; a[5] += wv * v1.y; a[6] += wv * v1.z; a[7] += wv * v1.w;
  }
#pragma unroll
  for (int j = 0; j < 8; ++j) {
    a[j] += __shfl_xor(a[j], 1);
    a[j] += __shfl_xor(a[j], 2);
  }
  if (l == 0) {
    float di = dis[n];
    const float4* mm = (const float4*)(m1s + (size_t)n * 8);
    float4 s0 = mm[0], s1 = mm[1];
    float h[8];
    h[0] = eluf(di * (a[0] + s0.x) + b1[0]);
    h[1] = eluf(di * (a[1] + s0.y) + b1[1]);
    h[2] = eluf(di * (a[2] + s0.z) + b1[2]);
    h[3] = eluf(di * (a[3] + s0.w) + b1[3]);
    h[4] = eluf(di * (a[4] + s1.x) + b1[4]);
    h[5] = eluf(di * (a[5] + s1.y) + b1[5]);
    h[6] = eluf(di * (a[6] + s1.z) + b1[6]);
    h[7] = eluf(di * (a[7] + s1.w) + b1[7]);
    float o0 = 0.f, o1 = 0.f, o2 = 0.f, o3 = 0.f;
#pragma unroll
    for (int i = 0; i < 8; ++i) {
      float hi = h[i];
      o0 += hi * W2[i * 4 + 0];
      o1 += hi * W2[i * 4 + 1];
      o2 += hi * W2[i * 4 + 2];
      o3 += hi * W2[i * 4 + 3];
    }
    *(float4*)(m2s + (size_t)n * 4) = make_float4(di * o0, di * o1, di * o2, di * o3);
  }
}

// Layer 2: 4 lanes per node; h2s = dis*elu(dis*(sum w*m2s[s] + m2s[n]) + b2).
__global__ __launch_bounds__(256) void layer2_kernel(const int2* __restrict__ recs2,
                                                     const int* __restrict__ nodeOff,
                                                     const float* __restrict__ m2s,
                                                     const float* __restrict__ dis,
                                                     const float* __restrict__ b2,
                                                     float* __restrict__ h2s) {
  const int tid = threadIdx.x;
  const int l = tid & 3;
  const int n = blockIdx.x * BN + (tid >> 2);
  if (n >= N_NODES) return;
  const int beg = nodeOff[n], end = nodeOff[n + 1];
  float a0 = 0.f, a1 = 0.f, a2 = 0.f, a3 = 0.f;
  for (int i = beg + l; i < end; i += 4) {
    int2 r = recs2[i];
    int s = r.x & 0x1FFFF;
    float wv = __int_as_float(r.y);
    float4 v = *(const float4*)(m2s + (size_t)s * 4);
    a0 += wv * v.x; a1 += wv * v.y; a2 += wv * v.z; a3 += wv * v.w;
  }
  a0 += __shfl_xor(a0, 1); a0 += __shfl_xor(a0, 2);
  a1 += __shfl_xor(a1, 1); a1 += __shfl_xor(a1, 2);
  a2 += __shfl_xor(a2, 1); a2 += __shfl_xor(a2, 2);
  a3 += __shfl_xor(a3, 1); a3 += __shfl_xor(a3, 2);
  if (l == 0) {
    float di = dis[n];
    float4 s = *(const float4*)(m2s + (size_t)n * 4);
    float4 r;
    r.x = di * eluf(di * (a0 + s.x) + b2[0]);
    r.y = di * eluf(di * (a1 + s.y) + b2[1]);
    r.z = di * eluf(di * (a2 + s.z) + b2[2]);
    r.w = di * eluf(di * (a3 + s.w) + b2[3]);
    *(float4*)(h2s + (size_t)n * 4) = r;
  }
}

// Layer 3: 4 lanes per node; out = (dis*(sum w*h2s[s] + h2s[n])) @ W3 + b3.
// Lane l stores columns 4l..4l+3 (fully coalesced float4 stores).
__global__ __launch_bounds__(256) void layer3_kernel(const int2* __restrict__ recs2,
                                                     const int* __restrict__ nodeOff,
                                                     const float* __restrict__ h2s,
                                                     const float* __restrict__ dis,
                                                     const float* __restrict__ b3,
                                                     const float* __restrict__ W3,
                                                     float* __restrict__ out) {
  const int tid = threadIdx.x;
  const int l = tid & 3;
  const int n = blockIdx.x * BN + (tid >> 2);
  if (n >= N_NODES) return;
  const int beg = nodeOff[n], end = nodeOff[n + 1];
  float a0 = 0.f, a1 = 0.f, a2 = 0.f, a3 = 0.f;
  for (int i = beg + l; i < end; i += 4) {
    int2 r = recs2[i];
    int s = r.x & 0x1FFFF;
    float wv = __int_as_float(r.y);
    float4 v = *(const float4*)(h2s + (size_t)s * 4);
    a0 += wv * v.x; a1 += wv * v.y; a2 += wv * v.z; a3 += wv * v.w;
  }
  a0 += __shfl_xor(a0, 1); a0 += __shfl_xor(a0, 2);
  a1 += __shfl_xor(a1, 1); a1 += __shfl_xor(a1, 2);
  a2 += __shfl_xor(a2, 1); a2 += __shfl_xor(a2, 2);
  a3 += __shfl_xor(a3, 1); a3 += __shfl_xor(a3, 2);
  float di = dis[n];
  float4 s = *(const float4*)(h2s + (size_t)n * 4);
  float g0 = di * (a0 + s.x);
  float g1 = di * (a1 + s.y);
  float g2 = di * (a2 + s.z);
  float g3 = di * (a3 + s.w);
  float o[4];
#pragma unroll
  for (int k = 0; k < 4; ++k) {
    int c = l * 4 + k;
    o[k] = b3[c] + g0 * W3[c] + g1 * W3[16 + c] + g2 * W3[32 + c] + g3 * W3[48 + c];
  }
  *(float4*)(out + (size_t)n * 16 + l * 4) = make_float4(o[0], o[1], o[2], o[3]);
}

extern "C" void kernel_launch(void* const* d_in, const int* in_sizes, int n_in,
                              void* d_out, int out_size, void* d_ws, size_t ws_size,
                              hipStream_t stream) {
  const float* x = (const float*)d_in[0];
  const void* ei = d_in[1];
  const float* w = (const float*)d_in[2];
  const float* W1 = (const float*)d_in[3];
  const float* b1 = (const float*)d_in[4];
  const float* W2 = (const float*)d_in[5];
  const float* b2 = (const float*)d_in[6];
  const float* W3 = (const float*)d_in[7];
  const float* b3 = (const float*)d_in[8];
  float* out = (float*)d_out;
  float* ws = (float*)d_ws;

  // ws layout (4-byte words). recs is dead after deg+nodesort, so the small
  // per-node feature buffers overlay its region (all writes happen after the
  // last recs read, stream-ordered).
  int2* recs = (int2*)ws;                         // [E] int2      (6,400,000 w)
  float* m1s = ws;                                // [8N] overlays recs
  float* m2s = ws + 800000;                       // [4N] overlays recs
  float* h2s = ws + 1200000;                      // [4N] overlays recs
  int2* recs2 = (int2*)(ws + 6400000);            // [E] int2      (6,400,000 w)
  int* cnt = (int*)(ws + 12800000);               // [NCHUNK*NBUK] (100,032 w)
  int* bucketBase = (int*)(ws + 12900032);        // [NBUK+1]      (1,564 w)
  float* dis = ws + 12901596;                     // [N]           (100,000 w)
  int* nodeOff = (int*)(ws + 13001596);           // [N+1]         (100,001 w)
  int* flag = (int*)(ws + 13101597);              // [1]
  // total ~= 13,101,598 words ~= 52.4 MB

  detect_kernel<<<1, 64, 0, stream>>>((const unsigned int*)ei, flag);
  count_kernel<<<NCHUNK, 512, 0, stream>>>(ei, flag, cnt);
  scan_kernel<<<1, 1024, 0, stream>>>(cnt, bucketBase);
  place_kernel<<<NCHUNK, 512, 0, stream>>>(ei, flag, w, cnt, bucketBase, recs);
  deg_kernel<<<NBUK, 256, 0, stream>>>(recs, bucketBase, dis);
  nodesort_kernel<<<NBUK, 256, 0, stream>>>(recs, bucketBase, recs2, nodeOff);
  transform1_kernel<<<4096, 256, 0, stream>>>(x, W1, dis, m1s);
  layer1_kernel<<<NBUK, 256, 0, stream>>>(recs2, nodeOff, m1s, dis, b1, W2, m2s);
  layer2_kernel<<<NBUK, 256, 0, stream>>>(recs2, nodeOff, m2s, dis, b2, h2s);
  layer3_kernel<<<NBUK, 256, 0, stream>>>(recs2, nodeOff, h2s, dis, b3, W3, out);
}

// Round 9
// 240.719 us; speedup vs baseline: 3.2111x; 1.3371x over previous
//
#include <hip/hip_runtime.h>
#include <math.h>

// GCN 3-layer forward, N=100000, E=3200000, F=256 -> 8 -> 4 -> 16.
// Round 9: NCHUNK back to 256 (place/count occupancy 5%->full machine) with a
// hierarchical scan: colscan (one wave per bucket, in-place exclusive prefix
// over chunks + bucket totals) + btscan (exclusive scan of 1563 totals).
// deg folded into nodesort's histogram pass. Layers = round-8 quad-gather
// (replay-proven).

#define N_NODES 100000
#define N_EDGES 3200000
#define BN 64                        // nodes per bucket
#define NBUK 1563                    // ceil(N/BN)
#define NCHUNK 256
#define CHUNK_E (N_EDGES / NCHUNK)   // 12500

__device__ __forceinline__ float eluf(float v) { return v > 0.0f ? v : expm1f(v); }

__device__ __forceinline__ void lds_add(float* p, float v) { unsafeAtomicAdd(p, v); }

__device__ __forceinline__ int ld_edge(const void* __restrict__ raw, int is64, long long idx) {
  return is64 ? (int)((const long long*)raw)[idx] : ((const int*)raw)[idx];
}

// Detect whether edge_index arrived as int64 (odd u32 words of first 64 all 0)
__global__ void detect_kernel(const unsigned int* __restrict__ ei, int* __restrict__ flag) {
  if (blockIdx.x == 0 && threadIdx.x == 0) {
    int is64 = 1;
    for (int i = 0; i < 32; ++i)
      if (ei[2 * i + 1] != 0u) { is64 = 0; break; }
    *flag = is64;
  }
}

// Phase A: per-(chunk,bucket) edge counts via LDS histogram (int atomics).
__global__ __launch_bounds__(512) void count_kernel(const void* __restrict__ raw,
                                                    const int* __restrict__ flag,
                                                    int* __restrict__ cnt) {
  __shared__ int c[NBUK];
  const int tid = threadIdx.x;
  for (int i = tid; i < NBUK; i += 512) c[i] = 0;
  __syncthreads();
  const int is64 = *flag;
  const int c0 = blockIdx.x * CHUNK_E;
  for (int e = c0 + tid; e < c0 + CHUNK_E; e += 512) {
    int d = ld_edge(raw, is64, (long long)N_EDGES + e);
    if ((unsigned)d < (unsigned)N_NODES) atomicAdd(&c[d >> 6], 1);
  }
  __syncthreads();
  for (int i = tid; i < NBUK; i += 512) cnt[blockIdx.x * NBUK + i] = c[i];
}

// Phase B1: one WAVE per bucket. In-place exclusive prefix of the bucket's
// 256 per-chunk counts (chunk order) + bucket total -> bucketBase[b].
__global__ __launch_bounds__(256) void colscan_kernel(int* __restrict__ cnt,
                                                      int* __restrict__ bucketBase) {
  const int b = blockIdx.x * 4 + (threadIdx.x >> 6);  // bucket = wave id
  const int lane = threadIdx.x & 63;
  if (b >= NBUK) return;
  int base = 0;
#pragma unroll
  for (int k = 0; k < NCHUNK / 64; ++k) {
    const int idx = (k * 64 + lane) * NBUK + b;
    int val = cnt[idx];
    int sc = val;
#pragma unroll
    for (int off = 1; off < 64; off <<= 1) {
      int u = __shfl_up(sc, off);
      if (lane >= off) sc += u;
    }
    cnt[idx] = base + sc - val;        // exclusive prefix over chunks
    base += __shfl(sc, 63);            // add group total
  }
  if (lane == 0) bucketBase[b] = base; // bucket total (scanned by btscan)
}

// Phase B2: in-place exclusive scan of bucketBase[0..NBUK-1], append total.
__global__ __launch_bounds__(1024) void btscan_kernel(int* __restrict__ bucketBase) {
  __shared__ int sdata[1024];
  __shared__ int sTA;
  const int t = threadIdx.x;
  const int b1 = 1024 + t;
  int T0 = (t < NBUK) ? bucketBase[t] : 0;
  int T1 = (b1 < NBUK) ? bucketBase[b1] : 0;
  sdata[t] = T0;
  __syncthreads();
  for (int off = 1; off < 1024; off <<= 1) {
    int v = (t >= off) ? sdata[t - off] : 0;
    __syncthreads();
    sdata[t] += v;
    __syncthreads();
  }
  int incl0 = sdata[t];
  if (t == 1023) sTA = sdata[1023];
  __syncthreads();
  const int TA = sTA;
  sdata[t] = T1;
  __syncthreads();
  for (int off = 1; off < 1024; off <<= 1) {
    int v = (t >= off) ? sdata[t - off] : 0;
    __syncthreads();
    sdata[t] += v;
    __syncthreads();
  }
  int incl1 = sdata[t];
  if (t < NBUK) bucketBase[t] = incl0 - T0;
  if (b1 < NBUK) bucketBase[b1] = TA + incl1 - T1;
  if (b1 == NBUK - 1) bucketBase[NBUK] = TA + incl1;
}

// Phase C: place records {src:17b | local:6b<<17, w} into bucket-grouped order.
// Every counted position gets written (invalid src -> zero-weight record).
__global__ __launch_bounds__(512) void place_kernel(const void* __restrict__ raw,
                                                    const int* __restrict__ flag,
                                                    const float* __restrict__ w,
                                                    const int* __restrict__ cnt,
                                                    const int* __restrict__ bucketBase,
                                                    int2* __restrict__ recs) {
  __shared__ int cur[NBUK];
  const int tid = threadIdx.x;
  for (int i = tid; i < NBUK; i += 512)
    cur[i] = cnt[blockIdx.x * NBUK + i] + bucketBase[i];
  __syncthreads();
  const int is64 = *flag;
  const int c0 = blockIdx.x * CHUNK_E;
  for (int e = c0 + tid; e < c0 + CHUNK_E; e += 512) {
    int s = ld_edge(raw, is64, e);
    int d = ld_edge(raw, is64, (long long)N_EDGES + e);
    if ((unsigned)d >= (unsigned)N_NODES) continue;
    float wv = w[e];
    if ((unsigned)s >= (unsigned)N_NODES) { s = 0; wv = 0.0f; }
    int bkt = d >> 6, loc = d & 63;
    int pos = atomicAdd(&cur[bkt], 1);
    recs[pos] = make_int2(s | (loc << 17), __float_as_int(wv));
  }
}

// Out-of-place node sort + fused weighted degree: per bucket, histogram by
// local node (+ wacc float adds), wave-0 scan -> nodeOff CSR + cursors +
// dis = rsqrt(wdeg+1), then place records into recs2 (node-grouped).
__global__ __launch_bounds__(256) void nodesort_kernel(const int2* __restrict__ recs,
                                                       const int* __restrict__ bucketBase,
                                                       int2* __restrict__ recs2,
                                                       int* __restrict__ nodeOff,
                                                       float* __restrict__ dis) {
  __shared__ int hist[BN];
  __shared__ int cur[BN];
  __shared__ float wacc[BN];
  const int b = blockIdx.x, tid = threadIdx.x;
  const int beg = bucketBase[b], end = bucketBase[b + 1];
  const int cnt = end - beg;
  if (tid < BN) { hist[tid] = 0; wacc[tid] = 0.0f; }
  __syncthreads();
  for (int i = tid; i < cnt; i += 256) {
    int2 r = recs[beg + i];
    int loc = (r.x >> 17) & 63;
    atomicAdd(&hist[loc], 1);
    lds_add(&wacc[loc], __int_as_float(r.y));
  }
  __syncthreads();
  if (tid < BN) {
    int v = hist[tid];
    int sc = v;
#pragma unroll
    for (int off = 1; off < BN; off <<= 1) {
      int u = __shfl_up(sc, off);
      if (tid >= off) sc += u;
    }
    int start = beg + sc - v;  // exclusive prefix within bucket
    cur[tid] = start;
    int n = b * BN + tid;
    if (n < N_NODES) {
      nodeOff[n] = start;
      dis[n] = rsqrtf(wacc[tid] + 1.0f);
    }
  }
  __syncthreads();
  for (int i = tid; i < cnt; i += 256) {
    int2 r = recs[beg + i];
    int pos = atomicAdd(&cur[(r.x >> 17) & 63], 1);
    recs2[pos] = r;
  }
  if (b == 0 && tid == 0) nodeOff[N_NODES] = bucketBase[NBUK];
}

// m1s[n] = dis[n] * (x[n] @ W1); one wave per node row (64 lanes x float4).
__global__ __launch_bounds__(256) void transform1_kernel(const float* __restrict__ x,
                                                         const float* __restrict__ W1,
                                                         const float* __restrict__ dis,
                                                         float* __restrict__ m1s) {
  const int lane = threadIdx.x & 63;
  const int gwave = blockIdx.x * 4 + (threadIdx.x >> 6);
  const int nwaves = gridDim.x * 4;
  float wreg[4][8];
#pragma unroll
  for (int i = 0; i < 4; ++i)
#pragma unroll
    for (int j = 0; j < 8; ++j)
      wreg[i][j] = W1[(lane * 4 + i) * 8 + j];
  for (int n = gwave; n < N_NODES; n += nwaves) {
    float4 xv = *(const float4*)(x + (size_t)n * 256 + lane * 4);
    float acc[8];
#pragma unroll
    for (int j = 0; j < 8; ++j)
      acc[j] = xv.x * wreg[0][j] + xv.y * wreg[1][j] + xv.z * wreg[2][j] + xv.w * wreg[3][j];
#pragma unroll
    for (int off = 32; off > 0; off >>= 1)
#pragma unroll
      for (int j = 0; j < 8; ++j)
        acc[j] += __shfl_down(acc[j], off);
    if (lane == 0) {
      float di = dis[n];
      float4* o = (float4*)(m1s + (size_t)n * 8);
      o[0] = make_float4(di * acc[0], di * acc[1], di * acc[2], di * acc[3]);
      o[1] = make_float4(di * acc[4], di * acc[5], di * acc[6], di * acc[7]);
    }
  }
}

// Layer 1: 4 lanes per node; acc[8] in registers; h = elu(dis*(sum w*m1s[s]
// + m1s[n]) + b1); m2s = dis*(h@W2). No atomics.
__global__ __launch_bounds__(256) void layer1_kernel(const int2* __restrict__ recs2,
                                                     const int* __restrict__ nodeOff,
                                                     const float* __restrict__ m1s,
                                                     const float* __restrict__ dis,
                                                     const float* __restrict__ b1,
                                                     const float* __restrict__ W2,
                                                     float* __restrict__ m2s) {
  const int tid = threadIdx.x;
  const int l = tid & 3;
  const int n = blockIdx.x * BN + (tid >> 2);
  if (n >= N_NODES) return;
  const int beg = nodeOff[n], end = nodeOff[n + 1];
  float a[8] = {0, 0, 0, 0, 0, 0, 0, 0};
  for (int i = beg + l; i < end; i += 4) {
    int2 r = recs2[i];
    int s = r.x & 0x1FFFF;
    float wv = __int_as_float(r.y);
    const float4* f = (const float4*)(m1s + (size_t)s * 8);
    float4 v0 = f[0], v1 = f[1];
    a[0] += wv * v0.x; a[1] += wv * v0.y; a[2] += wv * v0.z; a[3] += wv * v0.w;
    a[4] += wv * v1.x; a[5] += wv * v1.y; a[6] += wv * v1.z; a[7] += wv * v1.w;
  }
#pragma unroll
  for (int j = 0; j < 8; ++j) {
    a[j] += __shfl_xor(a[j], 1);
    a[j] += __shfl_xor(a[j], 2);
  }
  if (l == 0) {
    float di = dis[n];
    const float4* mm = (const float4*)(m1s + (size_t)n * 8);
    float4 s0 = mm[0], s1 = mm[1];
    float h[8];
    h[0] = eluf(di * (a[0] + s0.x) + b1[0]);
    h[1] = eluf(di * (a[1] + s0.y) + b1[1]);
    h[2] = eluf(di * (a[2] + s0.z) + b1[2]);
    h[3] = eluf(di * (a[3] + s0.w) + b1[3]);
    h[4] = eluf(di * (a[4] + s1.x) + b1[4]);
    h[5] = eluf(di * (a[5] + s1.y) + b1[5]);
    h[6] = eluf(di * (a[6] + s1.z) + b1[6]);
    h[7] = eluf(di * (a[7] + s1.w) + b1[7]);
    float o0 = 0.f, o1 = 0.f, o2 = 0.f, o3 = 0.f;
#pragma unroll
    for (int i = 0; i < 8; ++i) {
      float hi = h[i];
      o0 += hi * W2[i * 4 + 0];
      o1 += hi * W2[i * 4 + 1];
      o2 += hi * W2[i * 4 + 2];
      o3 += hi * W2[i * 4 + 3];
    }
    *(float4*)(m2s + (size_t)n * 4) = make_float4(di * o0, di * o1, di * o2, di * o3);
  }
}

// Layer 2: 4 lanes per node; h2s = dis*elu(dis*(sum w*m2s[s] + m2s[n]) + b2).
__global__ __launch_bounds__(256) void layer2_kernel(const int2* __restrict__ recs2,
                                                     const int* __restrict__ nodeOff,
                                                     const float* __restrict__ m2s,
                                                     const float* __restrict__ dis,
                                                     const float* __restrict__ b2,
                                                     float* __restrict__ h2s) {
  const int tid = threadIdx.x;
  const int l = tid & 3;
  const int n = blockIdx.x * BN + (tid >> 2);
  if (n >= N_NODES) return;
  const int beg = nodeOff[n], end = nodeOff[n + 1];
  float a0 = 0.f, a1 = 0.f, a2 = 0.f, a3 = 0.f;
  for (int i = beg + l; i < end; i += 4) {
    int2 r = recs2[i];
    int s = r.x & 0x1FFFF;
    float wv = __int_as_float(r.y);
    float4 v = *(const float4*)(m2s + (size_t)s * 4);
    a0 += wv * v.x; a1 += wv * v.y; a2 += wv * v.z; a3 += wv * v.w;
  }
  a0 += __shfl_xor(a0, 1); a0 += __shfl_xor(a0, 2);
  a1 += __shfl_xor(a1, 1); a1 += __shfl_xor(a1, 2);
  a2 += __shfl_xor(a2, 1); a2 += __shfl_xor(a2, 2);
  a3 += __shfl_xor(a3, 1); a3 += __shfl_xor(a3, 2);
  if (l == 0) {
    float di = dis[n];
    float4 s = *(const float4*)(m2s + (size_t)n * 4);
    float4 r;
    r.x = di * eluf(di * (a0 + s.x) + b2[0]);
    r.y = di * eluf(di * (a1 + s.y) + b2[1]);
    r.z = di * eluf(di * (a2 + s.z) + b2[2]);
    r.w = di * eluf(di * (a3 + s.w) + b2[3]);
    *(float4*)(h2s + (size_t)n * 4) = r;
  }
}

// Layer 3: 4 lanes per node; out = (dis*(sum w*h2s[s] + h2s[n])) @ W3 + b3.
// Lane l stores columns 4l..4l+3 (fully coalesced float4 stores).
__global__ __launch_bounds__(256) void layer3_kernel(const int2* __restrict__ recs2,
                                                     const int* __restrict__ nodeOff,
                                                     const float* __restrict__ h2s,
                                                     const float* __restrict__ dis,
                                                     const float* __restrict__ b3,
                                                     const float* __restrict__ W3,
                                                     float* __restrict__ out) {
  const int tid = threadIdx.x;
  const int l = tid & 3;
  const int n = blockIdx.x * BN + (tid >> 2);
  if (n >= N_NODES) return;
  const int beg = nodeOff[n], end = nodeOff[n + 1];
  float a0 = 0.f, a1 = 0.f, a2 = 0.f, a3 = 0.f;
  for (int i = beg + l; i < end; i += 4) {
    int2 r = recs2[i];
    int s = r.x & 0x1FFFF;
    float wv = __int_as_float(r.y);
    float4 v = *(const float4*)(h2s + (size_t)s * 4);
    a0 += wv * v.x; a1 += wv * v.y; a2 += wv * v.z; a3 += wv * v.w;
  }
  a0 += __shfl_xor(a0, 1); a0 += __shfl_xor(a0, 2);
  a1 += __shfl_xor(a1, 1); a1 += __shfl_xor(a1, 2);
  a2 += __shfl_xor(a2, 1); a2 += __shfl_xor(a2, 2);
  a3 += __shfl_xor(a3, 1); a3 += __shfl_xor(a3, 2);
  float di = dis[n];
  float4 s = *(const float4*)(h2s + (size_t)n * 4);
  float g0 = di * (a0 + s.x);
  float g1 = di * (a1 + s.y);
  float g2 = di * (a2 + s.z);
  float g3 = di * (a3 + s.w);
  float o[4];
#pragma unroll
  for (int k = 0; k < 4; ++k) {
    int c = l * 4 + k;
    o[k] = b3[c] + g0 * W3[c] + g1 * W3[16 + c] + g2 * W3[32 + c] + g3 * W3[48 + c];
  }
  *(float4*)(out + (size_t)n * 16 + l * 4) = make_float4(o[0], o[1], o[2], o[3]);
}

extern "C" void kernel_launch(void* const* d_in, const int* in_sizes, int n_in,
                              void* d_out, int out_size, void* d_ws, size_t ws_size,
                              hipStream_t stream) {
  const float* x = (const float*)d_in[0];
  const void* ei = d_in[1];
  const float* w = (const float*)d_in[2];
  const float* W1 = (const float*)d_in[3];
  const float* b1 = (const float*)d_in[4];
  const float* W2 = (const float*)d_in[5];
  const float* b2 = (const float*)d_in[6];
  const float* W3 = (const float*)d_in[7];
  const float* b3 = (const float*)d_in[8];
  float* out = (float*)d_out;
  float* ws = (float*)d_ws;

  // ws layout (4-byte words). recs is dead after nodesort, so the per-node
  // feature buffers overlay its region (writes happen after the last recs
  // read, stream-ordered).
  int2* recs = (int2*)ws;                         // [E] int2      (6,400,000 w)
  float* m1s = ws;                                // [8N] overlays recs
  float* m2s = ws + 800000;                       // [4N] overlays recs
  float* h2s = ws + 1200000;                      // [4N] overlays recs
  int2* recs2 = (int2*)(ws + 6400000);            // [E] int2      (6,400,000 w)
  int* cnt = (int*)(ws + 12800000);               // [NCHUNK*NBUK] (400,128 w)
  int* bucketBase = (int*)(ws + 13200128);        // [NBUK+1]      (1,564 w)
  float* dis = ws + 13201692;                     // [N]           (100,000 w)
  int* nodeOff = (int*)(ws + 13301692);           // [N+1]         (100,001 w)
  int* flag = (int*)(ws + 13401693);              // [1]
  // total ~= 13,401,694 words ~= 53.6 MB

  detect_kernel<<<1, 64, 0, stream>>>((const unsigned int*)ei, flag);
  count_kernel<<<NCHUNK, 512, 0, stream>>>(ei, flag, cnt);
  colscan_kernel<<<(NBUK + 3) / 4, 256, 0, stream>>>(cnt, bucketBase);
  btscan_kernel<<<1, 1024, 0, stream>>>(bucketBase);
  place_kernel<<<NCHUNK, 512, 0, stream>>>(ei, flag, w, cnt, bucketBase, recs);
  nodesort_kernel<<<NBUK, 256, 0, stream>>>(recs, bucketBase, recs2, nodeOff, dis);
  transform1_kernel<<<4096, 256, 0, stream>>>(x, W1, dis, m1s);
  layer1_kernel<<<NBUK, 256, 0, stream>>>(recs2, nodeOff, m1s, dis, b1, W2, m2s);
  layer2_kernel<<<NBUK, 256, 0, stream>>>(recs2, nodeOff, m2s, dis, b2, h2s);
  layer3_kernel<<<NBUK, 256, 0, stream>>>(recs2, nodeOff, h2s, dis, b3, W3, out);
}

// Round 10
// 237.321 us; speedup vs baseline: 3.2570x; 1.0143x over previous
//
#include <hip/hip_runtime.h>
#include <math.h>

// GCN 3-layer forward, N=100000, E=3200000, F=256 -> 8 -> 4 -> 16.
// Round 10: BN=128 buckets (longer place runs -> less write amp), NCHUNK=512
// (2 blocks/CU -> 50% occupancy cap for count/place), inline is64 detection
// (detect kernel dropped), nodesort at 512 threads with 2-wave 128-scan.
// Layers = quad-gather (replay-proven), BN-independent mapping.

#define N_NODES 100000
#define N_EDGES 3200000
#define BN 128                       // nodes per bucket
#define NBUK 782                     // ceil(N/BN)
#define NCHUNK 512
#define CHUNK_E (N_EDGES / NCHUNK)   // 6250

__device__ __forceinline__ float eluf(float v) { return v > 0.0f ? v : expm1f(v); }

__device__ __forceinline__ void lds_add(float* p, float v) { unsafeAtomicAdd(p, v); }

__device__ __forceinline__ int ld_edge(const void* __restrict__ raw, int is64, long long idx) {
  return is64 ? (int)((const long long*)raw)[idx] : ((const int*)raw)[idx];
}

// int64 edge_index has all-zero high words; int32 would have nonzero odd words.
__device__ __forceinline__ int detect_is64(const void* __restrict__ raw) {
  const unsigned* p = (const unsigned*)raw;
  int bad = 0;
#pragma unroll
  for (int i = 0; i < 32; ++i) bad |= (p[2 * i + 1] != 0u);
  return !bad;
}

// Phase A: per-(chunk,bucket) edge counts via LDS histogram (int atomics).
__global__ __launch_bounds__(512) void count_kernel(const void* __restrict__ raw,
                                                    int* __restrict__ cnt) {
  __shared__ int c[NBUK];
  const int tid = threadIdx.x;
  for (int i = tid; i < NBUK; i += 512) c[i] = 0;
  __syncthreads();
  const int is64 = detect_is64(raw);
  const int c0 = blockIdx.x * CHUNK_E;
  for (int e = c0 + tid; e < c0 + CHUNK_E; e += 512) {
    int d = ld_edge(raw, is64, (long long)N_EDGES + e);
    if ((unsigned)d < (unsigned)N_NODES) atomicAdd(&c[d >> 7], 1);
  }
  __syncthreads();
  for (int i = tid; i < NBUK; i += 512) cnt[blockIdx.x * NBUK + i] = c[i];
}

// Phase B1: one WAVE per bucket. In-place exclusive prefix of the bucket's
// 512 per-chunk counts (chunk order) + bucket total -> bucketBase[b].
__global__ __launch_bounds__(256) void colscan_kernel(int* __restrict__ cnt,
                                                      int* __restrict__ bucketBase) {
  const int b = blockIdx.x * 4 + (threadIdx.x >> 6);  // bucket = wave id
  const int lane = threadIdx.x & 63;
  if (b >= NBUK) return;
  int base = 0;
#pragma unroll
  for (int k = 0; k < NCHUNK / 64; ++k) {
    const int idx = (k * 64 + lane) * NBUK + b;
    int val = cnt[idx];
    int sc = val;
#pragma unroll
    for (int off = 1; off < 64; off <<= 1) {
      int u = __shfl_up(sc, off);
      if (lane >= off) sc += u;
    }
    cnt[idx] = base + sc - val;        // exclusive prefix over chunks
    base += __shfl(sc, 63);            // add group total
  }
  if (lane == 0) bucketBase[b] = base; // bucket total (scanned by btscan)
}

// Phase B2: in-place exclusive scan of bucketBase[0..NBUK-1] (NBUK<=1024),
// append grand total at bucketBase[NBUK].
__global__ __launch_bounds__(1024) void btscan_kernel(int* __restrict__ bucketBase) {
  __shared__ int sdata[1024];
  const int t = threadIdx.x;
  int T0 = (t < NBUK) ? bucketBase[t] : 0;
  sdata[t] = T0;
  __syncthreads();
  for (int off = 1; off < 1024; off <<= 1) {
    int v = (t >= off) ? sdata[t - off] : 0;
    __syncthreads();
    sdata[t] += v;
    __syncthreads();
  }
  if (t < NBUK) bucketBase[t] = sdata[t] - T0;
  if (t == NBUK - 1) bucketBase[NBUK] = sdata[t];
}

// Phase C: place records {src:17b | local:7b<<17, w} into bucket-grouped order.
// Every counted position gets written (invalid src -> zero-weight record).
__global__ __launch_bounds__(512) void place_kernel(const void* __restrict__ raw,
                                                    const float* __restrict__ w,
                                                    const int* __restrict__ cnt,
                                                    const int* __restrict__ bucketBase,
                                                    int2* __restrict__ recs) {
  __shared__ int cur[NBUK];
  const int tid = threadIdx.x;
  for (int i = tid; i < NBUK; i += 512)
    cur[i] = cnt[blockIdx.x * NBUK + i] + bucketBase[i];
  __syncthreads();
  const int is64 = detect_is64(raw);
  const int c0 = blockIdx.x * CHUNK_E;
  for (int e = c0 + tid; e < c0 + CHUNK_E; e += 512) {
    int s = ld_edge(raw, is64, e);
    int d = ld_edge(raw, is64, (long long)N_EDGES + e);
    if ((unsigned)d >= (unsigned)N_NODES) continue;
    float wv = w[e];
    if ((unsigned)s >= (unsigned)N_NODES) { s = 0; wv = 0.0f; }
    int bkt = d >> 7, loc = d & 127;
    int pos = atomicAdd(&cur[bkt], 1);
    recs[pos] = make_int2(s | (loc << 17), __float_as_int(wv));
  }
}

// Out-of-place node sort + fused weighted degree: per bucket (128 nodes),
// histogram by local node (+ wacc float adds), 2-wave scan -> nodeOff CSR +
// cursors + dis = rsqrt(wdeg+1), then place records into recs2 (node-grouped).
__global__ __launch_bounds__(512) void nodesort_kernel(const int2* __restrict__ recs,
                                                       const int* __restrict__ bucketBase,
                                                       int2* __restrict__ recs2,
                                                       int* __restrict__ nodeOff,
                                                       float* __restrict__ dis) {
  __shared__ int hist[BN];
  __shared__ int cur[BN];
  __shared__ float wacc[BN];
  __shared__ int wtot;  // wave-0 scan total
  const int b = blockIdx.x, tid = threadIdx.x;
  const int beg = bucketBase[b], end = bucketBase[b + 1];
  const int cnt = end - beg;
  if (tid < BN) { hist[tid] = 0; wacc[tid] = 0.0f; }
  __syncthreads();
  for (int i = tid; i < cnt; i += 512) {
    int2 r = recs[beg + i];
    int loc = (r.x >> 17) & 127;
    atomicAdd(&hist[loc], 1);
    lds_add(&wacc[loc], __int_as_float(r.y));
  }
  __syncthreads();
  int v = 0, sc = 0;
  if (tid < BN) {
    v = hist[tid];
    sc = v;
    const int lane = tid & 63;
#pragma unroll
    for (int off = 1; off < 64; off <<= 1) {
      int u = __shfl_up(sc, off);
      if (lane >= off) sc += u;
    }
    if (tid == 63) wtot = sc;  // wave-0 inclusive total
  }
  __syncthreads();
  if (tid < BN) {
    int base = (tid >= 64) ? wtot : 0;
    int start = beg + base + sc - v;  // exclusive prefix within bucket
    cur[tid] = start;
    int n = b * BN + tid;
    if (n < N_NODES) {
      nodeOff[n] = start;
      dis[n] = rsqrtf(wacc[tid] + 1.0f);
    }
  }
  __syncthreads();
  for (int i = tid; i < cnt; i += 512) {
    int2 r = recs[beg + i];
    int pos = atomicAdd(&cur[(r.x >> 17) & 127], 1);
    recs2[pos] = r;
  }
  if (b == 0 && tid == 0) nodeOff[N_NODES] = bucketBase[NBUK];
}

// m1s[n] = dis[n] * (x[n] @ W1); one wave per node row (64 lanes x float4).
__global__ __launch_bounds__(256) void transform1_kernel(const float* __restrict__ x,
                                                         const float* __restrict__ W1,
                                                         const float* __restrict__ dis,
                                                         float* __restrict__ m1s) {
  const int lane = threadIdx.x & 63;
  const int gwave = blockIdx.x * 4 + (threadIdx.x >> 6);
  const int nwaves = gridDim.x * 4;
  float wreg[4][8];
#pragma unroll
  for (int i = 0; i < 4; ++i)
#pragma unroll
    for (int j = 0; j < 8; ++j)
      wreg[i][j] = W1[(lane * 4 + i) * 8 + j];
  for (int n = gwave; n < N_NODES; n += nwaves) {
    float4 xv = *(const float4*)(x + (size_t)n * 256 + lane * 4);
    float acc[8];
#pragma unroll
    for (int j = 0; j < 8; ++j)
      acc[j] = xv.x * wreg[0][j] + xv.y * wreg[1][j] + xv.z * wreg[2][j] + xv.w * wreg[3][j];
#pragma unroll
    for (int off = 32; off > 0; off >>= 1)
#pragma unroll
      for (int j = 0; j < 8; ++j)
        acc[j] += __shfl_down(acc[j], off);
    if (lane == 0) {
      float di = dis[n];
      float4* o = (float4*)(m1s + (size_t)n * 8);
      o[0] = make_float4(di * acc[0], di * acc[1], di * acc[2], di * acc[3]);
      o[1] = make_float4(di * acc[4], di * acc[5], di * acc[6], di * acc[7]);
    }
  }
}

// Layer 1: 4 lanes per node; acc[8] in registers; h = elu(dis*(sum w*m1s[s]
// + m1s[n]) + b1); m2s = dis*(h@W2). No atomics.
__global__ __launch_bounds__(256) void layer1_kernel(const int2* __restrict__ recs2,
                                                     const int* __restrict__ nodeOff,
                                                     const float* __restrict__ m1s,
                                                     const float* __restrict__ dis,
                                                     const float* __restrict__ b1,
                                                     const float* __restrict__ W2,
                                                     float* __restrict__ m2s) {
  const int t = blockIdx.x * 256 + threadIdx.x;
  const int l = t & 3;
  const int n = t >> 2;
  if (n >= N_NODES) return;
  const int beg = nodeOff[n], end = nodeOff[n + 1];
  float a[8] = {0, 0, 0, 0, 0, 0, 0, 0};
  for (int i = beg + l; i < end; i += 4) {
    int2 r = recs2[i];
    int s = r.x & 0x1FFFF;
    float wv = __int_as_float(r.y);
    const float4* f = (const float4*)(m1s + (size_t)s * 8);
    float4 v0 = f[0], v1 = f[1];
    a[0] += wv * v0.x; a[1] += wv * v0.y; a[2] += wv * v0.z; a[3] += wv * v0.w;
    a[4] += wv * v1.x; a[5] += wv * v1.y; a[6] += wv * v1.z; a[7] += wv * v1.w;
  }
#pragma unroll
  for (int j = 0; j < 8; ++j) {
    a[j] += __shfl_xor(a[j], 1);
    a[j] += __shfl_xor(a[j], 2);
  }
  if (l == 0) {
    float di = dis[n];
    const float4* mm = (const float4*)(m1s + (size_t)n * 8);
    float4 s0 = mm[0], s1 = mm[1];
    float h[8];
    h[0] = eluf(di * (a[0] + s0.x) + b1[0]);
    h[1] = eluf(di * (a[1] + s0.y) + b1[1]);
    h[2] = eluf(di * (a[2] + s0.z) + b1[2]);
    h[3] = eluf(di * (a[3] + s0.w) + b1[3]);
    h[4] = eluf(di * (a[4] + s1.x) + b1[4]);
    h[5] = eluf(di * (a[5] + s1.y) + b1[5]);
    h[6] = eluf(di * (a[6] + s1.z) + b1[6]);
    h[7] = eluf(di * (a[7] + s1.w) + b1[7]);
    float o0 = 0.f, o1 = 0.f, o2 = 0.f, o3 = 0.f;
#pragma unroll
    for (int i = 0; i < 8; ++i) {
      float hi = h[i];
      o0 += hi * W2[i * 4 + 0];
      o1 += hi * W2[i * 4 + 1];
      o2 += hi * W2[i * 4 + 2];
      o3 += hi * W2[i * 4 + 3];
    }
    *(float4*)(m2s + (size_t)n * 4) = make_float4(di * o0, di * o1, di * o2, di * o3);
  }
}

// Layer 2: 4 lanes per node; h2s = dis*elu(dis*(sum w*m2s[s] + m2s[n]) + b2).
__global__ __launch_bounds__(256) void layer2_kernel(const int2* __restrict__ recs2,
                                                     const int* __restrict__ nodeOff,
                                                     const float* __restrict__ m2s,
                                                     const float* __restrict__ dis,
                                                     const float* __restrict__ b2,
                                                     float* __restrict__ h2s) {
  const int t = blockIdx.x * 256 + threadIdx.x;
  const int l = t & 3;
  const int n = t >> 2;
  if (n >= N_NODES) return;
  const int beg = nodeOff[n], end = nodeOff[n + 1];
  float a0 = 0.f, a1 = 0.f, a2 = 0.f, a3 = 0.f;
  for (int i = beg + l; i < end; i += 4) {
    int2 r = recs2[i];
    int s = r.x & 0x1FFFF;
    float wv = __int_as_float(r.y);
    float4 v = *(const float4*)(m2s + (size_t)s * 4);
    a0 += wv * v.x; a1 += wv * v.y; a2 += wv * v.z; a3 += wv * v.w;
  }
  a0 += __shfl_xor(a0, 1); a0 += __shfl_xor(a0, 2);
  a1 += __shfl_xor(a1, 1); a1 += __shfl_xor(a1, 2);
  a2 += __shfl_xor(a2, 1); a2 += __shfl_xor(a2, 2);
  a3 += __shfl_xor(a3, 1); a3 += __shfl_xor(a3, 2);
  if (l == 0) {
    float di = dis[n];
    float4 s = *(const float4*)(m2s + (size_t)n * 4);
    float4 r;
    r.x = di * eluf(di * (a0 + s.x) + b2[0]);
    r.y = di * eluf(di * (a1 + s.y) + b2[1]);
    r.z = di * eluf(di * (a2 + s.z) + b2[2]);
    r.w = di * eluf(di * (a3 + s.w) + b2[3]);
    *(float4*)(h2s + (size_t)n * 4) = r;
  }
}

// Layer 3: 4 lanes per node; out = (dis*(sum w*h2s[s] + h2s[n])) @ W3 + b3.
// Lane l stores columns 4l..4l+3 (fully coalesced float4 stores).
__global__ __launch_bounds__(256) void layer3_kernel(const int2* __restrict__ recs2,
                                                     const int* __restrict__ nodeOff,
                                                     const float* __restrict__ h2s,
                                                     const float* __restrict__ dis,
                                                     const float* __restrict__ b3,
                                                     const float* __restrict__ W3,
                                                     float* __restrict__ out) {
  const int t = blockIdx.x * 256 + threadIdx.x;
  const int l = t & 3;
  const int n = t >> 2;
  if (n >= N_NODES) return;
  const int beg = nodeOff[n], end = nodeOff[n + 1];
  float a0 = 0.f, a1 = 0.f, a2 = 0.f, a3 = 0.f;
  for (int i = beg + l; i < end; i += 4) {
    int2 r = recs2[i];
    int s = r.x & 0x1FFFF;
    float wv = __int_as_float(r.y);
    float4 v = *(const float4*)(h2s + (size_t)s * 4);
    a0 += wv * v.x; a1 += wv * v.y; a2 += wv * v.z; a3 += wv * v.w;
  }
  a0 += __shfl_xor(a0, 1); a0 += __shfl_xor(a0, 2);
  a1 += __shfl_xor(a1, 1); a1 += __shfl_xor(a1, 2);
  a2 += __shfl_xor(a2, 1); a2 += __shfl_xor(a2, 2);
  a3 += __shfl_xor(a3, 1); a3 += __shfl_xor(a3, 2);
  float di = dis[n];
  float4 s = *(const float4*)(h2s + (size_t)n * 4);
  float g0 = di * (a0 + s.x);
  float g1 = di * (a1 + s.y);
  float g2 = di * (a2 + s.z);
  float g3 = di * (a3 + s.w);
  float o[4];
#pragma unroll
  for (int k = 0; k < 4; ++k) {
    int c = l * 4 + k;
    o[k] = b3[c] + g0 * W3[c] + g1 * W3[16 + c] + g2 * W3[32 + c] + g3 * W3[48 + c];
  }
  *(float4*)(out + (size_t)n * 16 + l * 4) = make_float4(o[0], o[1], o[2], o[3]);
}

extern "C" void kernel_launch(void* const* d_in, const int* in_sizes, int n_in,
                              void* d_out, int out_size, void* d_ws, size_t ws_size,
                              hipStream_t stream) {
  const float* x = (const float*)d_in[0];
  const void* ei = d_in[1];
  const float* w = (const float*)d_in[2];
  const float* W1 = (const float*)d_in[3];
  const float* b1 = (const float*)d_in[4];
  const float* W2 = (const float*)d_in[5];
  const float* b2 = (const float*)d_in[6];
  const float* W3 = (const float*)d_in[7];
  const float* b3 = (const float*)d_in[8];
  float* out = (float*)d_out;
  float* ws = (float*)d_ws;

  // ws layout (4-byte words). recs is dead after nodesort, so the per-node
  // feature buffers overlay its region (writes happen after the last recs
  // read, stream-ordered).
  int2* recs = (int2*)ws;                         // [E] int2      (6,400,000 w)
  float* m1s = ws;                                // [8N] overlays recs
  float* m2s = ws + 800000;                       // [4N] overlays recs
  float* h2s = ws + 1200000;                      // [4N] overlays recs
  int2* recs2 = (int2*)(ws + 6400000);            // [E] int2      (6,400,000 w)
  int* cnt = (int*)(ws + 12800000);               // [NCHUNK*NBUK] (400,384 w)
  int* bucketBase = (int*)(ws + 13200384);        // [NBUK+1]      (783 w)
  float* dis = ws + 13201168;                     // [N]           (100,000 w)
  int* nodeOff = (int*)(ws + 13301168);           // [N+1]         (100,001 w)
  // total ~= 13,401,169 words ~= 53.6 MB

  count_kernel<<<NCHUNK, 512, 0, stream>>>(ei, cnt);
  colscan_kernel<<<(NBUK + 3) / 4, 256, 0, stream>>>(cnt, bucketBase);
  btscan_kernel<<<1, 1024, 0, stream>>>(bucketBase);
  place_kernel<<<NCHUNK, 512, 0, stream>>>(ei, w, cnt, bucketBase, recs);
  nodesort_kernel<<<NBUK, 512, 0, stream>>>(recs, bucketBase, recs2, nodeOff, dis);
  transform1_kernel<<<4096, 256, 0, stream>>>(x, W1, dis, m1s);
  const int NBL = (N_NODES * 4 + 255) / 256;  // 1563
  layer1_kernel<<<NBL, 256, 0, stream>>>(recs2, nodeOff, m1s, dis, b1, W2, m2s);
  layer2_kernel<<<NBL, 256, 0, stream>>>(recs2, nodeOff, m2s, dis, b2, h2s);
  layer3_kernel<<<NBL, 256, 0, stream>>>(recs2, nodeOff, h2s, dis, b3, W3, out);
}